// Round 13
// baseline (118.893 us; speedup 1.0000x reference)
//
#include <hip/hip_runtime.h>
#include <hip/hip_bf16.h>
#include <hip/hip_fp8.h>
#include <stdint.h>
#include <math.h>

#define NN 16384
#define DD 256
#define MARGIN_F 0.2f

typedef __attribute__((ext_vector_type(8))) int int32x8;
typedef __attribute__((ext_vector_type(4))) float f32x4;

// monotone order-preserving float<->uint key (max via unsigned atomicMax)
__device__ inline unsigned fkey(float f) {
    unsigned b = __float_as_uint(f);
    return (b & 0x80000000u) ? ~b : (b | 0x80000000u);
}
__device__ inline float fdec(unsigned k) {
    return __uint_as_float((k & 0x80000000u) ? (k ^ 0x80000000u) : ~k);
}
#define NEG_INF_KEY 0x007FFFFFu   // fkey(-inf)

__device__ inline void gload16(const void* g, void* l) {
    __builtin_amdgcn_global_load_lds(
        (const __attribute__((address_space(1))) void*)g,
        (__attribute__((address_space(3))) void*)l, 16, 0, 0);
}

__device__ inline unsigned pk8(float4 v) {
    __hip_fp8_e4m3 q0(v.x), q1(v.y), q2(v.z), q3(v.w);
    return (unsigned)q0.__x | ((unsigned)q1.__x << 8) |
           ((unsigned)q2.__x << 16) | ((unsigned)q3.__x << 24);
}

// ---------------- fused prep: f32->fp8 e4m3 + diag + init maxes ------------
__global__ __launch_bounds__(256) void fused_prep_kernel(
    const float* __restrict__ imgs, const float* __restrict__ caps,
    unsigned char* __restrict__ imgs8, unsigned char* __restrict__ caps8,
    float* __restrict__ diag, unsigned* __restrict__ rowmax,
    unsigned* __restrict__ colmax) {
    const int i = (blockIdx.x << 2) + (threadIdx.x >> 6);
    const int l = threadIdx.x & 63;
    const float4* a4 = reinterpret_cast<const float4*>(imgs + (size_t)i * DD);
    const float4* b4 = reinterpret_cast<const float4*>(caps + (size_t)i * DD);
    float4 av = a4[l];
    float4 bv = b4[l];
    reinterpret_cast<unsigned*>(imgs8 + (size_t)i * DD)[l] = pk8(av);
    reinterpret_cast<unsigned*>(caps8 + (size_t)i * DD)[l] = pk8(bv);
    float s = av.x * bv.x + av.y * bv.y + av.z * bv.z + av.w * bv.w;
    #pragma unroll
    for (int off = 32; off > 0; off >>= 1) s += __shfl_down(s, off);
    if (l == 0) {
        diag[i] = s;
        rowmax[i] = NEG_INF_KEY;
        colmax[i] = NEG_INF_KEY;
    }
}

// ---------------- main: A-resident strip kernel, MX-fp8, 128-col chunks ----
// 512 blocks = 128 row-panels x 4 col-strips. A panel (128x256 fp8 = 32KB)
// staged once via gload_lds -> af[4][2] int32x8 (64 VGPRs). B 128-col chunks
// (32KB fp8) double-buffered via gload_lds with 32B-pair XOR swizzle; counted
// vmcnt(8) pipeline; 32 chunk iterations (half the sync of 64-col chunks).
// colmax: per-lane reduce + 2 shfl + direct global atomic (no LDS pass).
__global__ __launch_bounds__(256, 2) void score_max_kernel(
    const unsigned char* __restrict__ imgs8,
    const unsigned char* __restrict__ caps8,
    const float* __restrict__ diag,
    unsigned* __restrict__ rowmax, unsigned* __restrict__ colmax) {

    __shared__ char lds[65536];   // A staged in [0,32K); B dbuf 2x32KB

    const int bid   = blockIdx.x;
    const int panel = bid >> 2;
    const int strip = bid & 3;
    const int brow  = panel << 7;
    const int scol  = strip << 12;

    const int t    = threadIdx.x;
    const int lane = t & 63;
    const int wid  = t >> 6;
    const int wr   = wid >> 1;    // 0..1: 64-row half
    const int wc   = wid & 1;     // 0..1: 32-col half within 64-col subchunk
    const int rg   = lane >> 4;   // 0..3
    const int cl   = lane & 15;   // 0..15

    // ---- staging geometry: granule d = t + 256*i; row = (t>>4)+16i,
    //      slot = t&15 (invariant). 32B-pair swizzle: pair' = pair ^ (row&7).
    const int sl = t & 15;
    const int rw = t >> 4;
    const int srcoff = (((sl >> 1) ^ (rw & 7)) << 5) + ((sl & 1) << 4);

    // ---- stage A panel (32KB fp8) into [0,32K) ----
    {
        const unsigned char* src = imgs8 + (((size_t)(brow + rw)) << 8) + srcoff;
        #pragma unroll
        for (int i = 0; i < 8; ++i)
            gload16(src + ((size_t)i << 12), lds + t * 16 + i * 4096);
    }
    __syncthreads();

    // ---- A fragments: af[m][ks], row = wr*64+m*16+cl, k = rg*32 (+ks*128) --
    int32x8 af[4][2];
    #pragma unroll
    for (int m = 0; m < 4; ++m) {
        const int row = wr * 64 + m * 16 + cl;
        #pragma unroll
        for (int ks = 0; ks < 2; ++ks)
            af[m][ks] = *reinterpret_cast<const int32x8*>(
                lds + row * 256 + (((rg + (ks << 2)) ^ (cl & 7)) << 5));
    }
    __syncthreads();   // done reading A before B overwrites

    // stage 32KB (128 rows) of B: 8 gloads/thread
    #define STAGEB(bo, cb) {                                                   \
        const unsigned char* s_ =                                              \
            caps8 + (((size_t)((cb) + rw)) << 8) + srcoff;                     \
        _Pragma("unroll")                                                      \
        for (int i_ = 0; i_ < 8; ++i_)                                         \
            gload16(s_ + ((size_t)i_ << 12), lds + (bo) + t * 16 + i_ * 4096); \
    }

    // prologue: issue stage(0) into buf0 (completion enforced at h=0 top)
    STAGEB(0, scol);

    float rmx[4][4];
    #pragma unroll
    for (int m = 0; m < 4; ++m)
        #pragma unroll
        for (int r = 0; r < 4; ++r) rmx[m][r] = -INFINITY;

    // ---- B-read byte offsets within a 64-col subchunk ----
    // row rr0 = wc*32+cl; n=1 -> +4096; subchunk c -> +16384 (row&7 invariant)
    const int rr0 = wc * 32 + cl;
    unsigned boff[2];
    #pragma unroll
    for (int ks = 0; ks < 2; ++ks)
        boff[ks] = rr0 * 256 + (((rg + (ks << 2)) ^ (cl & 7)) << 5);

    const f32x4 zv = (f32x4){0.f, 0.f, 0.f, 0.f};
    #define SCL 0x7F7F7F7F   // E8M0 exponent 127 = 1.0 in every byte

    for (int h = 0; h < 32; ++h) {
        const int cb = scol + (h << 7);
        const char* cur = lds + ((h & 1) << 15);

        // barrier 1: all waves done reading buf[(h+1)&1] (chunk h-1)
        __builtin_amdgcn_s_barrier();
        asm volatile("" ::: "memory");
        if (h < 31) {
            STAGEB(((h + 1) & 1) << 15, cb + 128);
            // oldest-beyond-8 = stage(h): wait it; stage(h+1) stays in flight
            asm volatile("s_waitcnt vmcnt(8)" ::: "memory");
        } else {
            asm volatile("s_waitcnt vmcnt(0)" ::: "memory");
        }
        // barrier 2: stage(h) visible to all waves
        __builtin_amdgcn_s_barrier();
        asm volatile("" ::: "memory");

        // ---- two 64-col subchunks ----
        #pragma unroll
        for (int c = 0; c < 2; ++c) {
            const int cbh = cb + (c << 6);
            const char* sb = cur + (c << 14);

            int32x8 b00 = *reinterpret_cast<const int32x8*>(sb + boff[0]);
            int32x8 b01 = *reinterpret_cast<const int32x8*>(sb + boff[0] + 4096);
            int32x8 b10 = *reinterpret_cast<const int32x8*>(sb + boff[1]);
            int32x8 b11 = *reinterpret_cast<const int32x8*>(sb + boff[1] + 4096);

            f32x4 acc[4][2];
            __builtin_amdgcn_s_setprio(1);
            #pragma unroll
            for (int m = 0; m < 4; ++m) {
                acc[m][0] = __builtin_amdgcn_mfma_scale_f32_16x16x128_f8f6f4(
                    af[m][0], b00, zv, 0, 0, 0, SCL, 0, SCL);
                acc[m][1] = __builtin_amdgcn_mfma_scale_f32_16x16x128_f8f6f4(
                    af[m][0], b01, zv, 0, 0, 0, SCL, 0, SCL);
            }
            #pragma unroll
            for (int m = 0; m < 4; ++m) {
                acc[m][0] = __builtin_amdgcn_mfma_scale_f32_16x16x128_f8f6f4(
                    af[m][1], b10, acc[m][0], 0, 0, 0, SCL, 0, SCL);
                acc[m][1] = __builtin_amdgcn_mfma_scale_f32_16x16x128_f8f6f4(
                    af[m][1], b11, acc[m][1], 0, 0, 0, SCL, 0, SCL);
            }
            __builtin_amdgcn_s_setprio(0);

            // ---- diagonal fix (exact f32) ----
            if (cbh < brow + 128 && cbh + 64 > brow) {
                #pragma unroll
                for (int m = 0; m < 4; ++m)
                    #pragma unroll
                    for (int r = 0; r < 4; ++r) {
                        const int i = brow + wr * 64 + m * 16 + (rg << 2) + r;
                        const int d = i - cbh - wc * 32;
                        #pragma unroll
                        for (int n = 0; n < 2; ++n)
                            if (d == n * 16 + cl) acc[m][n][r] = -diag[i];
                    }
            }

            // ---- running row-max (max3-fusable) ----
            #pragma unroll
            for (int m = 0; m < 4; ++m)
                #pragma unroll
                for (int r = 0; r < 4; ++r)
                    rmx[m][r] = fmaxf(fmaxf(rmx[m][r], acc[m][0][r]),
                                      acc[m][1][r]);

            // ---- col-max: per-lane reduce + 2 shfl + global atomic ----
            #pragma unroll
            for (int n = 0; n < 2; ++n) {
                float v = fmaxf(fmaxf(acc[0][n][0], acc[0][n][1]),
                                fmaxf(acc[0][n][2], acc[0][n][3]));
                #pragma unroll
                for (int m = 1; m < 4; ++m) {
                    v = fmaxf(fmaxf(v, acc[m][n][0]), acc[m][n][1]);
                    v = fmaxf(fmaxf(v, acc[m][n][2]), acc[m][n][3]);
                }
                v = fmaxf(v, __shfl_xor(v, 16));
                v = fmaxf(v, __shfl_xor(v, 32));
                if (rg == 0)
                    atomicMax(&colmax[cbh + wc * 32 + n * 16 + cl], fkey(v));
            }
        }
    }

    // ---- row-max writeout ----
    #pragma unroll
    for (int m = 0; m < 4; ++m)
        #pragma unroll
        for (int r = 0; r < 4; ++r) {
            float v = rmx[m][r];
            v = fmaxf(v, __shfl_xor(v, 1));
            v = fmaxf(v, __shfl_xor(v, 2));
            v = fmaxf(v, __shfl_xor(v, 4));
            v = fmaxf(v, __shfl_xor(v, 8));
            if (cl == 0)
                atomicMax(&rowmax[brow + wr * 64 + m * 16 + (rg << 2) + r],
                          fkey(v));
        }
    #undef STAGEB
}

// ---------------- finalize: hinge + total sum ----------------
__global__ __launch_bounds__(1024) void finalize_kernel(
    const float* __restrict__ diag,
    const unsigned* __restrict__ rowmax,
    const unsigned* __restrict__ colmax,
    float* __restrict__ out) {
    __shared__ float red[1024];
    int t = threadIdx.x;
    float s = 0.f;
    for (int idx = t; idx < 2 * NN; idx += 1024) {
        int i = idx & (NN - 1);
        float mx = fdec((idx < NN) ? colmax[i] : rowmax[i]);
        s += fmaxf(mx + (MARGIN_F - diag[i]), 0.f);
    }
    red[t] = s;
    __syncthreads();
    for (int off = 512; off > 0; off >>= 1) {
        if (t < off) red[t] += red[t + off];
        __syncthreads();
    }
    if (t == 0) out[0] = red[0];
}

extern "C" void kernel_launch(void* const* d_in, const int* in_sizes, int n_in,
                              void* d_out, int out_size, void* d_ws, size_t ws_size,
                              hipStream_t stream) {
    const float* imgs = reinterpret_cast<const float*>(d_in[0]);
    const float* caps = reinterpret_cast<const float*>(d_in[1]);

    float* diag          = reinterpret_cast<float*>(d_ws);
    unsigned* rowmax     = reinterpret_cast<unsigned*>(diag + NN);
    unsigned* colmax     = rowmax + NN;
    unsigned char* imgs8 = reinterpret_cast<unsigned char*>(colmax + NN);
    unsigned char* caps8 = imgs8 + (size_t)NN * DD;

    fused_prep_kernel<<<NN / 4, 256, 0, stream>>>(imgs, caps, imgs8, caps8,
                                                  diag, rowmax, colmax);

    score_max_kernel<<<512, 256, 0, stream>>>(imgs8, caps8, diag,
                                              rowmax, colmax);

    finalize_kernel<<<1, 1024, 0, stream>>>(diag, rowmax, colmax,
                                            reinterpret_cast<float*>(d_out));
}